// Round 19
// baseline (407.641 us; speedup 1.0000x reference)
//
#include <hip/hip_runtime.h>
#include <math.h>

#define TB    4096
#define TSEQ  320
#define NEEG  64
#define NTH   32
#define NH    16
#define NGEO  18
#define TILE_T 64
#define NTILES 5
#define XROWS2 70
#define H1ROWS 66
#define NGEOBLK ((TB/16)*80)   // 20480 geo blocks appended to conv grid

typedef _Float16 f16x8 __attribute__((ext_vector_type(8)));
typedef _Float16 f16x2 __attribute__((ext_vector_type(2)));
typedef float f32x4 __attribute__((ext_vector_type(4)));
#define INV2048 4.8828125e-4f

// ws float offsets
#define OFF_W1F  0        // 10240 floats = 20480 halves: [kk][nb][hl][64][8]
#define OFF_W2F  10240    // 1536 floats = 3072 halves:   [kk2][hl][64][8]
#define OFF_B1   11776    // 32
#define OFF_B2   11808    // 16
#define OFF_GWT  11824    // 288  [i][h]
#define OFF_FC1T 12112    // 10240 [f][o]
#define OFF_FC2T 22352    // 256   [j][o]
#define OFF_ZP   22656    // 64 floats of zeros (DMA zero page)
#define OFF_E    32768    // E: [t4][b][h][4]
#define SZ_EC    (TB*TSEQ*NH)
#define OFF_C    (OFF_E + SZ_EC)

__global__ void __launch_bounds__(256)
prep_kernel(const float* __restrict__ c1w, const float* __restrict__ c1b,
            const float* __restrict__ s1,  const float* __restrict__ bb1,
            const float* __restrict__ mm1, const float* __restrict__ vv1,
            const float* __restrict__ c2w, const float* __restrict__ c2b,
            const float* __restrict__ s2,  const float* __restrict__ bb2,
            const float* __restrict__ mm2, const float* __restrict__ vv2,
            const float* __restrict__ gw,  const float* __restrict__ fc1w,
            const float* __restrict__ fc2w, float* __restrict__ ws)
{
    const int tid = threadIdx.x;
    _Float16* w1fp = reinterpret_cast<_Float16*>(ws + OFF_W1F);
    _Float16* w2fp = reinterpret_cast<_Float16*>(ws + OFF_W2F);

    for (int d = tid; d < 10240; d += 256) {
        int j = d & 7, l = (d >> 3) & 63, nbk = d >> 9;
        int kk = nbk >> 1, nb = nbk & 1;
        int k = kk >> 1, i = (kk & 1) * 32 + ((l >> 4) * 8) + j;
        int c = nb * 16 + (l & 15);
        float inv = s1[c] / sqrtf(vv1[c] + 1e-5f);
        float wv = c1w[c * 320 + i * 5 + k] * inv;
        _Float16 hi = (_Float16)wv;
        _Float16 lo = (_Float16)((wv - (float)hi) * 2048.f);
        w1fp[((nbk * 2 + 0) * 64 + l) * 8 + j] = hi;
        w1fp[((nbk * 2 + 1) * 64 + l) * 8 + j] = lo;
    }
    for (int d = tid; d < 1536; d += 256) {
        int j = d & 7, l = (d >> 3) & 63, kk2 = d >> 9;
        int c = (l >> 4) * 8 + j;
        int o = l & 15;
        float inv = s2[o] / sqrtf(vv2[o] + 1e-5f);
        float wv = c2w[o * 96 + c * 3 + kk2] * inv;
        _Float16 hi = (_Float16)wv;
        _Float16 lo = (_Float16)((wv - (float)hi) * 2048.f);
        w2fp[((kk2 * 2 + 0) * 64 + l) * 8 + j] = hi;
        w2fp[((kk2 * 2 + 1) * 64 + l) * 8 + j] = lo;
    }
    if (tid < NTH) {
        float inv = s1[tid] / sqrtf(vv1[tid] + 1e-5f);
        ws[OFF_B1 + tid] = c1b[tid] * inv + bb1[tid] - mm1[tid] * inv;
    }
    if (tid < NH) {
        float inv = s2[tid] / sqrtf(vv2[tid] + 1e-5f);
        ws[OFF_B2 + tid] = c2b[tid] * inv + bb2[tid] - mm2[tid] * inv;
    }
    for (int d = tid; d < NGEO * NH; d += 256) {
        int i = d / NH, h = d - i * NH;
        ws[OFF_GWT + d] = gw[h * NGEO + i];
    }
    for (int d = tid; d < 160 * 64; d += 256) {
        int f = d / 64, o = d - f * 64;
        ws[OFF_FC1T + d] = fc1w[o * 160 + f];
    }
    if (tid < 256) {
        int j = tid / 4, o = tid - j * 4;
        ws[OFF_FC2T + tid] = fc2w[o * 64 + j];
    }
    if (tid < 64) ws[OFF_ZP + tid] = 0.f;
}

// ---------- Kernel A: conv blocks (bid < TB) + geo backfill blocks (bid >= TB) ----------
__global__ void __launch_bounds__(256, 2)
convm_kernel(const float* __restrict__ xeeg, const float* __restrict__ xgeo,
             const float* __restrict__ ws,   const float* __restrict__ geo_b,
             const float* __restrict__ gamma,
             float* __restrict__ E, float* __restrict__ C)
{
    __shared__ __align__(16) float xbuf[2][XROWS2 * 64];     // 35840 B
    __shared__ __align__(16) _Float16 h1h[H1ROWS * 32];      // 4224 B
    __shared__ __align__(16) _Float16 h1l[H1ROWS * 32];      // 4224 B
    __shared__ float b1s[32], b2s[16];
    __shared__ float xgs[16][72];                            // 4608 B (geo path)
    __shared__ float gws_l[NGEO * NH];                       // 1152 B (geo path)
    __shared__ float gb_l[16], gam_l[16];

    const int tid = threadIdx.x;

    // ================= GEO PATH (backfill blocks) =================
    if (blockIdx.x >= TB) {
        const int g = blockIdx.x - TB;
        const int b0 = (g & 255) * 16;     // TB/16 == 256
        const int t4 = g >> 8;             // 0..79

        for (int p = tid; p < NGEO * NH; p += 256) gws_l[p] = ws[OFF_GWT + p];
        if (tid < 16) { gb_l[tid] = geo_b[tid]; gam_l[tid] = gamma[tid]; }
        for (int p = tid; p < 16 * 72; p += 256) {
            int bb = p / 72, r = p - bb * 72;
            xgs[bb][r] = xgeo[(size_t)(b0 + bb) * (TSEQ * NGEO) + (size_t)t4 * 72 + r];
        }
        __syncthreads();

        const int h = tid & 15, bl = tid >> 4;
        float4 cv;
        float* cvp = reinterpret_cast<float*>(&cv);
        #pragma unroll
        for (int tt = 0; tt < 4; ++tt) {
            float z = gb_l[h];
            const float* xr = &xgs[bl][tt * 18];
            #pragma unroll
            for (int ii = 0; ii < NGEO; ++ii)
                z = fmaf(xr[ii], gws_l[ii * 16 + h], z);
            cvp[tt] = gam_l[h] * (1.f / (1.f + expf(-z)));
        }
        float* cp = C + (((size_t)t4 * TB + (b0 + bl)) * 16 + h) * 4;
        *reinterpret_cast<float4*>(cp) = cv;
        return;
    }

    // ================= CONV PATH =================
    const int b = blockIdx.x;
    const int l = tid & 63, w = tid >> 6;
    const int lrow = l & 15, lkg = l >> 4;
    const int nb = w >> 1, wsub = w & 1;

    const float* xb = xeeg + (size_t)b * TSEQ * NEEG;
    const float* zp = ws + OFF_ZP;

#define STAGE_DMA(buf, t0n) do {                                                     \
        for (int c_ = w; c_ < XROWS2; c_ += 4) {                                     \
            int tg_ = (t0n) - 3 + c_;                                                \
            const float* s_ = (tg_ >= 0 && tg_ < TSEQ)                               \
                              ? (xb + (size_t)tg_ * 64 + l) : zp;                    \
            __builtin_amdgcn_global_load_lds(                                        \
                (const __attribute__((address_space(1))) void*)s_,                   \
                (__attribute__((address_space(3))) void*)&xbuf[(buf)][c_ * 64],      \
                4, 0, 0);                                                            \
        }                                                                            \
    } while (0)

    f16x8 B1h[10], B1l[10], B2h[3], B2l[3];
    {
        const f16x8* wsrc = reinterpret_cast<const f16x8*>(ws + OFF_W1F);
        #pragma unroll
        for (int kk = 0; kk < 10; ++kk) {
            B1h[kk] = wsrc[((kk * 2 + nb) * 2 + 0) * 64 + l];
            B1l[kk] = wsrc[((kk * 2 + nb) * 2 + 1) * 64 + l];
        }
        const f16x8* wsrc2 = reinterpret_cast<const f16x8*>(ws + OFF_W2F);
        #pragma unroll
        for (int kk = 0; kk < 3; ++kk) {
            B2h[kk] = wsrc2[(kk * 2 + 0) * 64 + l];
            B2l[kk] = wsrc2[(kk * 2 + 1) * 64 + l];
        }
    }
    if (tid < 32) b1s[tid] = ws[OFF_B1 + tid];
    if (tid < 16) b2s[tid] = ws[OFF_B2 + tid];

    STAGE_DMA(0, 0);
    __syncthreads();

    for (int jt = 0; jt < NTILES; ++jt) {
        const int t0 = jt * TILE_T;
        const int cur = jt & 1;
        _Float16* xh = reinterpret_cast<_Float16*>(&xbuf[cur][0]);
        _Float16* xl = xh + XROWS2 * 64;

        float2 xr2[9];
        #pragma unroll
        for (int q = 0; q < 9; ++q) {
            int p = tid + q * 256;
            if (p < 2240) {
                int xr = p >> 5, ip = (p & 31) * 2;
                xr2[q] = *reinterpret_cast<const float2*>(&xbuf[cur][xr * 64 + ip]);
            }
        }
        __syncthreads();   // barrier S1

        #pragma unroll
        for (int q = 0; q < 9; ++q) {
            int p = tid + q * 256;
            if (p < 2240) {
                int xr = p >> 5, ip = (p & 31) * 2;
                float f0 = xr2[q].x, f1 = xr2[q].y;
                _Float16 h0 = (_Float16)f0, h1v = (_Float16)f1;
                f16x2 vh = {h0, h1v};
                f16x2 vl = {(_Float16)((f0 - (float)h0) * 2048.f),
                            (_Float16)((f1 - (float)h1v) * 2048.f)};
                int idx = xr * 64 + (((ip >> 3) ^ (xr & 7)) << 3) + (ip & 7);
                *reinterpret_cast<f16x2*>(&xh[idx]) = vh;
                *reinterpret_cast<f16x2*>(&xl[idx]) = vl;
            }
        }
        __syncthreads();   // barrier A

        if (jt + 1 < NTILES) STAGE_DMA(cur ^ 1, (jt + 1) * TILE_T);
        __builtin_amdgcn_s_setprio(1);
        {
            const float bia = b1s[nb * 16 + lrow];
            #pragma unroll
            for (int pi = 0; pi < 3; ++pi) {
                if (pi == 2 && ((jt & 1) != wsub)) break;
                const int mb = (pi < 2) ? (wsub + pi * 2) : 4;
                const int mbase = mb * 16;
                int s = mbase + lrow; if (s > 65) s = 65;
                f32x4 aH = {0.f, 0.f, 0.f, 0.f};
                f32x4 aM = aH, aL = aH;
                #pragma unroll
                for (int kk = 0; kk < 10; ++kk) {
                    const int xr = s + (kk >> 1);
                    const int gx = (kk & 1) * 4 + lkg;
                    const int off = xr * 64 + ((gx ^ (xr & 7)) << 3);
                    f16x8 Ah = *reinterpret_cast<const f16x8*>(&xh[off]);
                    f16x8 Al = *reinterpret_cast<const f16x8*>(&xl[off]);
                    aH = __builtin_amdgcn_mfma_f32_16x16x32_f16(Ah, B1h[kk], aH, 0, 0, 0);
                    aM = __builtin_amdgcn_mfma_f32_16x16x32_f16(Ah, B1l[kk], aM, 0, 0, 0);
                    aL = __builtin_amdgcn_mfma_f32_16x16x32_f16(Al, B1h[kk], aL, 0, 0, 0);
                }
                #pragma unroll
                for (int r = 0; r < 4; ++r) {
                    int so = mbase + lkg * 4 + r;
                    if (so < 66) {
                        int tg = t0 - 1 + so;
                        bool v = (tg >= 0 && tg < TSEQ);
                        float val = v ? fmaxf(fmaf(aM[r] + aL[r], INV2048, aH[r]) + bia, 0.f) : 0.f;
                        int key = (so >> 1) & 3;
                        int g = (nb * 2 + (lrow >> 3)) ^ key;
                        int idx = so * 32 + (g << 3) + (lrow & 7);
                        _Float16 hh = (_Float16)val;
                        h1h[idx] = hh;
                        h1l[idx] = (_Float16)((val - (float)hh) * 2048.f);
                    }
                }
            }
        }
        __builtin_amdgcn_s_setprio(0);
        __syncthreads();   // barrier B

        {
            const int ub = w * 16;
            f32x4 aH = {0.f, 0.f, 0.f, 0.f};
            f32x4 aM = aH, aL = aH;
            __builtin_amdgcn_s_setprio(1);
            #pragma unroll
            for (int kk = 0; kk < 3; ++kk) {
                int srow = ub + lrow + kk;
                int off = srow * 32 + ((lkg ^ ((srow >> 1) & 3)) << 3);
                f16x8 Ah = *reinterpret_cast<const f16x8*>(&h1h[off]);
                f16x8 Al = *reinterpret_cast<const f16x8*>(&h1l[off]);
                aH = __builtin_amdgcn_mfma_f32_16x16x32_f16(Ah, B2h[kk], aH, 0, 0, 0);
                aM = __builtin_amdgcn_mfma_f32_16x16x32_f16(Ah, B2l[kk], aM, 0, 0, 0);
                aL = __builtin_amdgcn_mfma_f32_16x16x32_f16(Al, B2h[kk], aL, 0, 0, 0);
            }
            __builtin_amdgcn_s_setprio(0);
            const float bia = b2s[lrow];
            float4 ev;
            float* evp = reinterpret_cast<float*>(&ev);
            #pragma unroll
            for (int r = 0; r < 4; ++r)
                evp[r] = fmaxf(fmaf(aM[r] + aL[r], INV2048, aH[r]) + bia, 0.f);
            const int t4o = ((t0 + ub) >> 2) + lkg;
            float* ep = E + (((size_t)t4o * TB + b) * 16 + lrow) * 4;
            *reinterpret_cast<float4*>(ep) = ev;
        }
    }
#undef STAGE_DMA
}

// ---------- Kernel B: ALIF scan (quad-slab prefetch) + fused fc; 16 b's per block ----------
__global__ void __launch_bounds__(256)
scanfc_kernel(const float* __restrict__ E, const float* __restrict__ C,
              const float* __restrict__ ws, const float* __restrict__ fc1_b,
              const float* __restrict__ fc2_b, float* __restrict__ out)
{
    __shared__ float dp_lds[16][160];       // 10240 B
    __shared__ float mid[16][64];           // 4096 B

    const int tid = threadIdx.x;
    const int h = tid & 15, bl = tid >> 4;
    const int b0 = blockIdx.x * 16;
    const int b = b0 + bl;

    const float4* e4 = reinterpret_cast<const float4*>(E);
    const float4* c4 = reinterpret_cast<const float4*>(C);
    const size_t slab = (size_t)TB * 16;
    const size_t idx = (size_t)b * 16 + h;

    float eta = 0.f, memv = 0.f, li = 0.f, ps = 0.f, accF = 0.f, accS = 0.f;

    float4 eA[4], cA[4], eB[4], cB[4];

#define LOADQ(EB, CB, lq) do {                                                   \
        if ((lq) < 20) {                                                         \
            _Pragma("unroll")                                                    \
            for (int j = 0; j < 4; ++j) {                                        \
                EB[j] = e4[(size_t)((lq) * 4 + j) * slab + idx];                 \
                CB[j] = c4[(size_t)((lq) * 4 + j) * slab + idx];                 \
            }                                                                    \
        }                                                                        \
    } while (0)

#define PROCQ(EB, CB, q) do {                                                    \
        _Pragma("unroll")                                                        \
        for (int j = 0; j < 4; ++j) {                                            \
            const int t4_ = (q) * 4 + j;                                         \
            const float* evp = reinterpret_cast<const float*>(&EB[j]);           \
            const float* cvp = reinterpret_cast<const float*>(&CB[j]);           \
            _Pragma("unroll")                                                    \
            for (int tt = 0; tt < 4; ++tt) {                                     \
                float e = evp[tt], c = cvp[tt];                                  \
                eta = 0.36f * eta + 0.64f * ps;                                  \
                float theta = 0.5f + 1.8f * eta - c;                             \
                memv = 0.8f * memv + e;                                          \
                float spk = (memv - theta >= 0.f) ? 1.f : 0.f;                   \
                memv *= (1.f - spk);                                             \
                li = 0.9f * li + spk;                                            \
                ps = spk;                                                        \
                int t = t4_ * 4 + tt;                                            \
                if (((t >> 4) & 1) == 0) accF += li; else accS += li;            \
            }                                                                    \
            if ((t4_ & 7) == 7) {                                                \
                dp_lds[bl][h * 10 + (t4_ >> 3)] = (accS - accF) * 0.0625f;       \
                accF = 0.f; accS = 0.f;                                          \
            }                                                                    \
        }                                                                        \
    } while (0)

    LOADQ(eA, cA, 0);
    for (int qp = 0; qp < 10; ++qp) {
        const int q0 = qp * 2, q1 = qp * 2 + 1;
        LOADQ(eB, cB, q1);
        PROCQ(eA, cA, q0);
        LOADQ(eA, cA, q1 + 1);
        PROCQ(eB, cB, q1);
    }
#undef LOADQ
#undef PROCQ
    __syncthreads();   // dp complete

    // ---- fc1 + ReLU: 16 b x 64 o = 1024 tasks, 4 per thread ----
    {
        const float* __restrict__ fc1t = ws + OFF_FC1T;
        #pragma unroll
        for (int k = 0; k < 4; ++k) {
            int id = tid + k * 256;
            int bb = id >> 6, o = id & 63;
            float z = fc1_b[o];
            for (int f = 0; f < 160; ++f)
                z = fmaf(dp_lds[bb][f], fc1t[f * 64 + o], z);
            mid[bb][o] = fmaxf(z, 0.f);
        }
    }
    __syncthreads();
    // ---- fc2: 16 b x 4 o ----
    if (tid < 64) {
        const float* __restrict__ fc2t = ws + OFF_FC2T;
        int bb = tid >> 2, oo = tid & 3;
        float z = fc2_b[oo];
        #pragma unroll
        for (int jj = 0; jj < 64; ++jj)
            z = fmaf(mid[bb][jj], fc2t[jj * 4 + oo], z);
        out[(size_t)(b0 + bb) * 4 + oo] = z;
    }
}

extern "C" void kernel_launch(void* const* d_in, const int* in_sizes, int n_in,
                              void* d_out, int out_size, void* d_ws, size_t ws_size,
                              hipStream_t stream)
{
    const float* xeeg = (const float*)d_in[0];
    const float* xgeo = (const float*)d_in[1];
    const float* c1w  = (const float*)d_in[2];
    const float* c1b  = (const float*)d_in[3];
    const float* s1   = (const float*)d_in[4];
    const float* bb1  = (const float*)d_in[5];
    const float* mm1  = (const float*)d_in[6];
    const float* vv1  = (const float*)d_in[7];
    const float* c2w  = (const float*)d_in[8];
    const float* c2b  = (const float*)d_in[9];
    const float* s2   = (const float*)d_in[10];
    const float* bb2  = (const float*)d_in[11];
    const float* mm2  = (const float*)d_in[12];
    const float* vv2  = (const float*)d_in[13];
    const float* gw   = (const float*)d_in[14];
    const float* gb   = (const float*)d_in[15];
    const float* gam  = (const float*)d_in[16];
    const float* fc1w = (const float*)d_in[17];
    const float* fc1b = (const float*)d_in[18];
    const float* fc2w = (const float*)d_in[19];
    const float* fc2b = (const float*)d_in[20];
    float* ws   = (float*)d_ws;
    float* outp = (float*)d_out;

    hipLaunchKernelGGL(prep_kernel, dim3(1), dim3(256), 0, stream,
                       c1w, c1b, s1, bb1, mm1, vv1, c2w, c2b, s2, bb2, mm2, vv2,
                       gw, fc1w, fc2w, ws);

    float* E = ws + OFF_E;
    float* C = ws + OFF_C;
    hipLaunchKernelGGL(convm_kernel, dim3(TB + NGEOBLK), dim3(256), 0, stream,
                       xeeg, xgeo, ws, gb, gam, E, C);
    hipLaunchKernelGGL(scanfc_kernel, dim3(TB / 16), dim3(256), 0, stream,
                       E, C, ws, fc1b, fc2b, outp);
}

// Round 21
// 300.602 us; speedup vs baseline: 1.3561x; 1.3561x over previous
//
#include <hip/hip_runtime.h>
#include <math.h>

#define TB    4096
#define TSEQ  320
#define NEEG  64
#define NTH   32
#define NH    16
#define NGEO  18
#define TILE_T 64
#define NTILES 5
#define XROWS2 70
#define H1ROWS 66

typedef _Float16 f16x8 __attribute__((ext_vector_type(8)));
typedef _Float16 f16x2 __attribute__((ext_vector_type(2)));
typedef float f32x4 __attribute__((ext_vector_type(4)));
#define INV2048 4.8828125e-4f

// ws float offsets
#define OFF_W1F  0        // 10240 floats = 20480 halves: [kk][nb][hl][64][8]
#define OFF_W2F  10240    // 1536 floats = 3072 halves:   [kk2][hl][64][8]
#define OFF_B1   11776    // 32
#define OFF_B2   11808    // 16
#define OFF_GWT  11824    // 288  [i][h]
#define OFF_FC1T 12112    // 10240 [f][o]
#define OFF_FC2T 22352    // 256   [j][o]
#define OFF_ZP   22656    // 64 floats of zeros (DMA zero page)
#define OFF_E    32768    // E: [t4][b][h][4]
#define SZ_EC    (TB*TSEQ*NH)
#define OFF_C    (OFF_E + SZ_EC)

__global__ void __launch_bounds__(256)
prep_kernel(const float* __restrict__ c1w, const float* __restrict__ c1b,
            const float* __restrict__ s1,  const float* __restrict__ bb1,
            const float* __restrict__ mm1, const float* __restrict__ vv1,
            const float* __restrict__ c2w, const float* __restrict__ c2b,
            const float* __restrict__ s2,  const float* __restrict__ bb2,
            const float* __restrict__ mm2, const float* __restrict__ vv2,
            const float* __restrict__ gw,  const float* __restrict__ fc1w,
            const float* __restrict__ fc2w, float* __restrict__ ws)
{
    const int tid = threadIdx.x;
    _Float16* w1fp = reinterpret_cast<_Float16*>(ws + OFF_W1F);
    _Float16* w2fp = reinterpret_cast<_Float16*>(ws + OFF_W2F);

    for (int d = tid; d < 10240; d += 256) {
        int j = d & 7, l = (d >> 3) & 63, nbk = d >> 9;
        int kk = nbk >> 1, nb = nbk & 1;
        int k = kk >> 1, i = (kk & 1) * 32 + ((l >> 4) * 8) + j;
        int c = nb * 16 + (l & 15);
        float inv = s1[c] / sqrtf(vv1[c] + 1e-5f);
        float wv = c1w[c * 320 + i * 5 + k] * inv;
        _Float16 hi = (_Float16)wv;
        _Float16 lo = (_Float16)((wv - (float)hi) * 2048.f);
        w1fp[((nbk * 2 + 0) * 64 + l) * 8 + j] = hi;
        w1fp[((nbk * 2 + 1) * 64 + l) * 8 + j] = lo;
    }
    for (int d = tid; d < 1536; d += 256) {
        int j = d & 7, l = (d >> 3) & 63, kk2 = d >> 9;
        int c = (l >> 4) * 8 + j;
        int o = l & 15;
        float inv = s2[o] / sqrtf(vv2[o] + 1e-5f);
        float wv = c2w[o * 96 + c * 3 + kk2] * inv;
        _Float16 hi = (_Float16)wv;
        _Float16 lo = (_Float16)((wv - (float)hi) * 2048.f);
        w2fp[((kk2 * 2 + 0) * 64 + l) * 8 + j] = hi;
        w2fp[((kk2 * 2 + 1) * 64 + l) * 8 + j] = lo;
    }
    if (tid < NTH) {
        float inv = s1[tid] / sqrtf(vv1[tid] + 1e-5f);
        ws[OFF_B1 + tid] = c1b[tid] * inv + bb1[tid] - mm1[tid] * inv;
    }
    if (tid < NH) {
        float inv = s2[tid] / sqrtf(vv2[tid] + 1e-5f);
        ws[OFF_B2 + tid] = c2b[tid] * inv + bb2[tid] - mm2[tid] * inv;
    }
    for (int d = tid; d < NGEO * NH; d += 256) {
        int i = d / NH, h = d - i * NH;
        ws[OFF_GWT + d] = gw[h * NGEO + i];
    }
    for (int d = tid; d < 160 * 64; d += 256) {
        int f = d / 64, o = d - f * 64;
        ws[OFF_FC1T + d] = fc1w[o * 160 + f];
    }
    if (tid < 256) {
        int j = tid / 4, o = tid - j * 4;
        ws[OFF_FC2T + tid] = fc2w[o * 64 + j];
    }
    if (tid < 64) ws[OFF_ZP + tid] = 0.f;
}

// ---------- Kernel A: MFMA conv1+conv2 (geo-free, r18 verbatim) ----------
__global__ void __launch_bounds__(256, 2)
convm_kernel(const float* __restrict__ xeeg, const float* __restrict__ ws,
             float* __restrict__ E)
{
    __shared__ __align__(16) float xbuf[2][XROWS2 * 64];     // 35840 B
    __shared__ __align__(16) _Float16 h1h[H1ROWS * 32];      // 4224 B
    __shared__ __align__(16) _Float16 h1l[H1ROWS * 32];      // 4224 B
    __shared__ float b1s[32], b2s[16];

    const int b = blockIdx.x, tid = threadIdx.x;
    const int l = tid & 63, w = tid >> 6;
    const int lrow = l & 15, lkg = l >> 4;
    const int nb = w >> 1, wsub = w & 1;

    const float* xb = xeeg + (size_t)b * TSEQ * NEEG;
    const float* zp = ws + OFF_ZP;

#define STAGE_DMA(buf, t0n) do {                                                     \
        for (int c_ = w; c_ < XROWS2; c_ += 4) {                                     \
            int tg_ = (t0n) - 3 + c_;                                                \
            const float* s_ = (tg_ >= 0 && tg_ < TSEQ)                               \
                              ? (xb + (size_t)tg_ * 64 + l) : zp;                    \
            __builtin_amdgcn_global_load_lds(                                        \
                (const __attribute__((address_space(1))) void*)s_,                   \
                (__attribute__((address_space(3))) void*)&xbuf[(buf)][c_ * 64],      \
                4, 0, 0);                                                            \
        }                                                                            \
    } while (0)

    f16x8 B1h[10], B1l[10], B2h[3], B2l[3];
    {
        const f16x8* wsrc = reinterpret_cast<const f16x8*>(ws + OFF_W1F);
        #pragma unroll
        for (int kk = 0; kk < 10; ++kk) {
            B1h[kk] = wsrc[((kk * 2 + nb) * 2 + 0) * 64 + l];
            B1l[kk] = wsrc[((kk * 2 + nb) * 2 + 1) * 64 + l];
        }
        const f16x8* wsrc2 = reinterpret_cast<const f16x8*>(ws + OFF_W2F);
        #pragma unroll
        for (int kk = 0; kk < 3; ++kk) {
            B2h[kk] = wsrc2[(kk * 2 + 0) * 64 + l];
            B2l[kk] = wsrc2[(kk * 2 + 1) * 64 + l];
        }
    }
    if (tid < 32) b1s[tid] = ws[OFF_B1 + tid];
    if (tid < 16) b2s[tid] = ws[OFF_B2 + tid];

    STAGE_DMA(0, 0);
    __syncthreads();

    for (int jt = 0; jt < NTILES; ++jt) {
        const int t0 = jt * TILE_T;
        const int cur = jt & 1;
        _Float16* xh = reinterpret_cast<_Float16*>(&xbuf[cur][0]);
        _Float16* xl = xh + XROWS2 * 64;

        float2 xr2[9];
        #pragma unroll
        for (int q = 0; q < 9; ++q) {
            int p = tid + q * 256;
            if (p < 2240) {
                int xr = p >> 5, ip = (p & 31) * 2;
                xr2[q] = *reinterpret_cast<const float2*>(&xbuf[cur][xr * 64 + ip]);
            }
        }
        __syncthreads();   // barrier S1

        #pragma unroll
        for (int q = 0; q < 9; ++q) {
            int p = tid + q * 256;
            if (p < 2240) {
                int xr = p >> 5, ip = (p & 31) * 2;
                float f0 = xr2[q].x, f1 = xr2[q].y;
                _Float16 h0 = (_Float16)f0, h1v = (_Float16)f1;
                f16x2 vh = {h0, h1v};
                f16x2 vl = {(_Float16)((f0 - (float)h0) * 2048.f),
                            (_Float16)((f1 - (float)h1v) * 2048.f)};
                int idx = xr * 64 + (((ip >> 3) ^ (xr & 7)) << 3) + (ip & 7);
                *reinterpret_cast<f16x2*>(&xh[idx]) = vh;
                *reinterpret_cast<f16x2*>(&xl[idx]) = vl;
            }
        }
        __syncthreads();   // barrier A

        if (jt + 1 < NTILES) STAGE_DMA(cur ^ 1, (jt + 1) * TILE_T);
        __builtin_amdgcn_s_setprio(1);
        {
            const float bia = b1s[nb * 16 + lrow];
            #pragma unroll
            for (int pi = 0; pi < 3; ++pi) {
                if (pi == 2 && ((jt & 1) != wsub)) break;
                const int mb = (pi < 2) ? (wsub + pi * 2) : 4;
                const int mbase = mb * 16;
                int s = mbase + lrow; if (s > 65) s = 65;
                f32x4 aH = {0.f, 0.f, 0.f, 0.f};
                f32x4 aM = aH, aL = aH;
                #pragma unroll
                for (int kk = 0; kk < 10; ++kk) {
                    const int xr = s + (kk >> 1);
                    const int gx = (kk & 1) * 4 + lkg;
                    const int off = xr * 64 + ((gx ^ (xr & 7)) << 3);
                    f16x8 Ah = *reinterpret_cast<const f16x8*>(&xh[off]);
                    f16x8 Al = *reinterpret_cast<const f16x8*>(&xl[off]);
                    aH = __builtin_amdgcn_mfma_f32_16x16x32_f16(Ah, B1h[kk], aH, 0, 0, 0);
                    aM = __builtin_amdgcn_mfma_f32_16x16x32_f16(Ah, B1l[kk], aM, 0, 0, 0);
                    aL = __builtin_amdgcn_mfma_f32_16x16x32_f16(Al, B1h[kk], aL, 0, 0, 0);
                }
                #pragma unroll
                for (int r = 0; r < 4; ++r) {
                    int so = mbase + lkg * 4 + r;
                    if (so < 66) {
                        int tg = t0 - 1 + so;
                        bool v = (tg >= 0 && tg < TSEQ);
                        float val = v ? fmaxf(fmaf(aM[r] + aL[r], INV2048, aH[r]) + bia, 0.f) : 0.f;
                        int key = (so >> 1) & 3;
                        int g = (nb * 2 + (lrow >> 3)) ^ key;
                        int idx = so * 32 + (g << 3) + (lrow & 7);
                        _Float16 hh = (_Float16)val;
                        h1h[idx] = hh;
                        h1l[idx] = (_Float16)((val - (float)hh) * 2048.f);
                    }
                }
            }
        }
        __builtin_amdgcn_s_setprio(0);
        __syncthreads();   // barrier B

        {
            const int ub = w * 16;
            f32x4 aH = {0.f, 0.f, 0.f, 0.f};
            f32x4 aM = aH, aL = aH;
            __builtin_amdgcn_s_setprio(1);
            #pragma unroll
            for (int kk = 0; kk < 3; ++kk) {
                int srow = ub + lrow + kk;
                int off = srow * 32 + ((lkg ^ ((srow >> 1) & 3)) << 3);
                f16x8 Ah = *reinterpret_cast<const f16x8*>(&h1h[off]);
                f16x8 Al = *reinterpret_cast<const f16x8*>(&h1l[off]);
                aH = __builtin_amdgcn_mfma_f32_16x16x32_f16(Ah, B2h[kk], aH, 0, 0, 0);
                aM = __builtin_amdgcn_mfma_f32_16x16x32_f16(Ah, B2l[kk], aM, 0, 0, 0);
                aL = __builtin_amdgcn_mfma_f32_16x16x32_f16(Al, B2h[kk], aL, 0, 0, 0);
            }
            __builtin_amdgcn_s_setprio(0);
            const float bia = b2s[lrow];
            float4 ev;
            float* evp = reinterpret_cast<float*>(&ev);
            #pragma unroll
            for (int r = 0; r < 4; ++r)
                evp[r] = fmaxf(fmaf(aM[r] + aL[r], INV2048, aH[r]) + bia, 0.f);
            const int t4o = ((t0 + ub) >> 2) + lkg;
            float* ep = E + (((size_t)t4o * TB + b) * 16 + lrow) * 4;
            *reinterpret_cast<float4*>(ep) = ev;
        }
    }
#undef STAGE_DMA
}

// ---------- Kernel G: geo -> C [t4][b][h][4]; 16 b x 16 t per block ----------
__global__ void __launch_bounds__(256)
geo_kernel(const float* __restrict__ xgeo, const float* __restrict__ ws,
           const float* __restrict__ geo_b, const float* __restrict__ gamma,
           float* __restrict__ C)
{
    __shared__ float xgs[16][288];          // 18432 B (16 b x 16 t x 18)
    __shared__ float gws_l[NGEO * NH];      // 1152 B
    __shared__ float gb_l[16], gam_l[16];

    const int tid = threadIdx.x;
    const int b0 = blockIdx.x * 16;
    const int s0 = blockIdx.y * 4;          // first t4 of this block's window

    for (int p = tid; p < NGEO * NH; p += 256) gws_l[p] = ws[OFF_GWT + p];
    if (tid < 16) { gb_l[tid] = geo_b[tid]; gam_l[tid] = gamma[tid]; }
    {
        const float4* xg4 = reinterpret_cast<const float4*>(xgeo);
        // per-b row = 1440 float4; 16-t window at t4=s0 starts at s0*18 float4 (72 floats)
        for (int p = tid; p < 1152; p += 256) {      // 16 b x 72 float4
            int bb = p / 72, r = p - bb * 72;
            reinterpret_cast<float4*>(&xgs[bb][0])[r] =
                xg4[(size_t)(b0 + bb) * 1440 + (size_t)s0 * 18 + r];
        }
    }
    __syncthreads();

    const int h = tid & 15, bl = tid >> 4;
    #pragma unroll
    for (int k = 0; k < 4; ++k) {
        const int t4 = s0 + k;
        float4 cv;
        float* cvp = reinterpret_cast<float*>(&cv);
        #pragma unroll
        for (int tt = 0; tt < 4; ++tt) {
            float z = gb_l[h];
            const float* xr = &xgs[bl][(k * 4 + tt) * 18];
            #pragma unroll
            for (int ii = 0; ii < NGEO; ++ii)
                z = fmaf(xr[ii], gws_l[ii * 16 + h], z);
            cvp[tt] = gam_l[h] * (1.f / (1.f + expf(-z)));
        }
        float* cp = C + (((size_t)t4 * TB + (b0 + bl)) * 16 + h) * 4;
        *reinterpret_cast<float4*>(cp) = cv;
    }
}

// ---------- Kernel B: ALIF scan (quad-slab prefetch, r19 verbatim) + fused fc ----------
__global__ void __launch_bounds__(256)
scanfc_kernel(const float* __restrict__ E, const float* __restrict__ C,
              const float* __restrict__ ws, const float* __restrict__ fc1_b,
              const float* __restrict__ fc2_b, float* __restrict__ out)
{
    __shared__ float dp_lds[16][160];       // 10240 B
    __shared__ float mid[16][64];           // 4096 B

    const int tid = threadIdx.x;
    const int h = tid & 15, bl = tid >> 4;
    const int b0 = blockIdx.x * 16;
    const int b = b0 + bl;

    const float4* e4 = reinterpret_cast<const float4*>(E);
    const float4* c4 = reinterpret_cast<const float4*>(C);
    const size_t slab = (size_t)TB * 16;
    const size_t idx = (size_t)b * 16 + h;

    float eta = 0.f, memv = 0.f, li = 0.f, ps = 0.f, accF = 0.f, accS = 0.f;

    float4 eA[4], cA[4], eB[4], cB[4];

#define LOADQ(EB, CB, lq) do {                                                   \
        if ((lq) < 20) {                                                         \
            _Pragma("unroll")                                                    \
            for (int j = 0; j < 4; ++j) {                                        \
                EB[j] = e4[(size_t)((lq) * 4 + j) * slab + idx];                 \
                CB[j] = c4[(size_t)((lq) * 4 + j) * slab + idx];                 \
            }                                                                    \
        }                                                                        \
    } while (0)

#define PROCQ(EB, CB, q) do {                                                    \
        _Pragma("unroll")                                                        \
        for (int j = 0; j < 4; ++j) {                                            \
            const int t4_ = (q) * 4 + j;                                         \
            const float* evp = reinterpret_cast<const float*>(&EB[j]);           \
            const float* cvp = reinterpret_cast<const float*>(&CB[j]);           \
            _Pragma("unroll")                                                    \
            for (int tt = 0; tt < 4; ++tt) {                                     \
                float e = evp[tt], c = cvp[tt];                                  \
                eta = 0.36f * eta + 0.64f * ps;                                  \
                float theta = 0.5f + 1.8f * eta - c;                             \
                memv = 0.8f * memv + e;                                          \
                float spk = (memv - theta >= 0.f) ? 1.f : 0.f;                   \
                memv *= (1.f - spk);                                             \
                li = 0.9f * li + spk;                                            \
                ps = spk;                                                        \
                int t = t4_ * 4 + tt;                                            \
                if (((t >> 4) & 1) == 0) accF += li; else accS += li;            \
            }                                                                    \
            if ((t4_ & 7) == 7) {                                                \
                dp_lds[bl][h * 10 + (t4_ >> 3)] = (accS - accF) * 0.0625f;       \
                accF = 0.f; accS = 0.f;                                          \
            }                                                                    \
        }                                                                        \
    } while (0)

    LOADQ(eA, cA, 0);
    for (int qp = 0; qp < 10; ++qp) {
        const int q0 = qp * 2, q1 = qp * 2 + 1;
        LOADQ(eB, cB, q1);
        PROCQ(eA, cA, q0);
        LOADQ(eA, cA, q1 + 1);
        PROCQ(eB, cB, q1);
    }
#undef LOADQ
#undef PROCQ
    __syncthreads();   // dp complete

    {
        const float* __restrict__ fc1t = ws + OFF_FC1T;
        #pragma unroll
        for (int k = 0; k < 4; ++k) {
            int id = tid + k * 256;
            int bb = id >> 6, o = id & 63;
            float z = fc1_b[o];
            for (int f = 0; f < 160; ++f)
                z = fmaf(dp_lds[bb][f], fc1t[f * 64 + o], z);
            mid[bb][o] = fmaxf(z, 0.f);
        }
    }
    __syncthreads();
    if (tid < 64) {
        const float* __restrict__ fc2t = ws + OFF_FC2T;
        int bb = tid >> 2, oo = tid & 3;
        float z = fc2_b[oo];
        #pragma unroll
        for (int jj = 0; jj < 64; ++jj)
            z = fmaf(mid[bb][jj], fc2t[jj * 4 + oo], z);
        out[(size_t)(b0 + bb) * 4 + oo] = z;
    }
}

extern "C" void kernel_launch(void* const* d_in, const int* in_sizes, int n_in,
                              void* d_out, int out_size, void* d_ws, size_t ws_size,
                              hipStream_t stream)
{
    const float* xeeg = (const float*)d_in[0];
    const float* xgeo = (const float*)d_in[1];
    const float* c1w  = (const float*)d_in[2];
    const float* c1b  = (const float*)d_in[3];
    const float* s1   = (const float*)d_in[4];
    const float* bb1  = (const float*)d_in[5];
    const float* mm1  = (const float*)d_in[6];
    const float* vv1  = (const float*)d_in[7];
    const float* c2w  = (const float*)d_in[8];
    const float* c2b  = (const float*)d_in[9];
    const float* s2   = (const float*)d_in[10];
    const float* bb2  = (const float*)d_in[11];
    const float* mm2  = (const float*)d_in[12];
    const float* vv2  = (const float*)d_in[13];
    const float* gw   = (const float*)d_in[14];
    const float* gb   = (const float*)d_in[15];
    const float* gam  = (const float*)d_in[16];
    const float* fc1w = (const float*)d_in[17];
    const float* fc1b = (const float*)d_in[18];
    const float* fc2w = (const float*)d_in[19];
    const float* fc2b = (const float*)d_in[20];
    float* ws   = (float*)d_ws;
    float* outp = (float*)d_out;

    hipLaunchKernelGGL(prep_kernel, dim3(1), dim3(256), 0, stream,
                       c1w, c1b, s1, bb1, mm1, vv1, c2w, c2b, s2, bb2, mm2, vv2,
                       gw, fc1w, fc2w, ws);

    float* E = ws + OFF_E;
    float* C = ws + OFF_C;
    hipLaunchKernelGGL(geo_kernel, dim3(TB / 16, TSEQ / 16), dim3(256), 0, stream,
                       xgeo, ws, gb, gam, C);
    hipLaunchKernelGGL(convm_kernel, dim3(TB), dim3(256), 0, stream,
                       xeeg, ws, E);
    hipLaunchKernelGGL(scanfc_kernel, dim3(TB / 16), dim3(256), 0, stream,
                       E, C, ws, fc1b, fc2b, outp);
}